// Round 6
// baseline (408.912 us; speedup 1.0000x reference)
//
#include <hip/hip_runtime.h>
#include <hip/hip_cooperative_groups.h>
#include <math.h>

namespace cg = cooperative_groups;

#define NPROT 50000
#define NPROT_PAD 50048
#define EPPI 500000
#define NPAIR 4096

typedef __attribute__((ext_vector_type(8))) __bf16 bf16x8;
typedef __attribute__((ext_vector_type(4))) __bf16 bf16x4;
typedef __attribute__((ext_vector_type(4))) float floatx4;

// ---------- cooperative build: prep + hist + scan + fill in ONE kernel ----------
// grid = 256 blocks x 256 threads (co-resident: ~1KB LDS, low VGPR)
__global__ void k_build(const float* __restrict__ x,
                        const float* __restrict__ Wl, const float* __restrict__ Wr,
                        const float* __restrict__ linW, const float* __restrict__ linb,
                        const float* __restrict__ bWl, const float* __restrict__ bWr,
                        const float* __restrict__ bb,
                        const int* __restrict__ src, const int* __restrict__ dst,
                        __bf16* __restrict__ Xb, __bf16* __restrict__ Bw,
                        float* __restrict__ P, float* __restrict__ biasC,
                        int* __restrict__ cnt, int* __restrict__ rowptr,
                        int* __restrict__ cursor, float* __restrict__ inv,
                        int* __restrict__ blocksum, int* __restrict__ ssrc) {
    cg::grid_group grid = cg::this_grid();
    __shared__ int sd[256];
    __shared__ float sP[12];
    int b = blockIdx.x, t = threadIdx.x;
    int gid = b * 256 + t;               // 0..65535
    int lane = t & 63, wave = t >> 6;

    // ---- phase A: zero cnt, cast Xb, pack Bw, compute P/biasC ----
    if (gid < NPROT) cnt[gid] = 0;
    for (int i = gid; i < NPROT * 32; i += 65536) {
        int row = i >> 5, k4 = (i & 31) << 2;
        float4 v = *(const float4*)(x + (size_t)row * 128 + k4);
        bf16x4 o; o[0] = (__bf16)v.x; o[1] = (__bf16)v.y; o[2] = (__bf16)v.z; o[3] = (__bf16)v.w;
        *(bf16x4*)(Xb + (size_t)row * 128 + k4) = o;
    }
    {   // Bw[h][k]: k<128 -> aWl, else aWr
        int h = gid >> 8, k = gid & 255;
        float v = (k < 128) ? Wl[h * 128 + k] : Wr[h * 128 + (k - 128)];
        Bw[gid] = (__bf16)v;
    }
    {   // P[b][0..3] via 128-wide parallel dot; block b handles output column h=b
        float v1 = 0, v2 = 0, u1 = 0, u2 = 0, c = 0;
        if (t < 128) {
            float w1 = linW[t], w2 = linW[128 + t];
            float wl = bWl[t * 256 + b], wr = bWr[t * 256 + b];
            v1 = w1 * wl; v2 = w2 * wl; u1 = w1 * wr; u2 = w2 * wr;
            if (b == 0) c = (w1 + w2) * bb[t];
        }
#pragma unroll
        for (int m = 1; m < 64; m <<= 1) {
            v1 += __shfl_xor(v1, m, 64); v2 += __shfl_xor(v2, m, 64);
            u1 += __shfl_xor(u1, m, 64); u2 += __shfl_xor(u2, m, 64);
            c  += __shfl_xor(c, m, 64);
        }
        if (lane == 0 && wave < 2) {
            sP[wave * 6 + 0] = v1; sP[wave * 6 + 1] = v2;
            sP[wave * 6 + 2] = u1; sP[wave * 6 + 3] = u2;
            sP[wave * 6 + 4] = c;
        }
        __syncthreads();
        if (t == 0) {
            P[b * 4 + 0] = sP[0] + sP[6]; P[b * 4 + 1] = sP[1] + sP[7];
            P[b * 4 + 2] = sP[2] + sP[8]; P[b * 4 + 3] = sP[3] + sP[9];
            if (b == 0) *biasC = linb[0] + sP[4] + sP[10];
        }
    }
    grid.sync();

    // ---- phase B: histogram ----
    for (int e = gid; e < EPPI; e += 65536) atomicAdd(&cnt[dst[e]], 1);
    grid.sync();

    // ---- phase C: scan (block scan + block-prefix) ----
    int v = (gid < NPROT) ? cnt[gid] : 0;
    sd[t] = v;
    __syncthreads();
    int xv = v;
    for (int off = 1; off < 256; off <<= 1) {
        int add = (t >= off) ? sd[t - off] : 0;
        __syncthreads();
        xv += add;
        sd[t] = xv;
        __syncthreads();
    }
    if (t == 255) blocksum[b] = xv;
    grid.sync();
    {
        int pv = (t < b) ? blocksum[t] : 0;
        __syncthreads();
        sd[t] = pv;
        __syncthreads();
        for (int off = 128; off > 0; off >>= 1) {
            if (t < off) sd[t] += sd[t + off];
            __syncthreads();
        }
        int r = sd[0] + xv - v;          // global exclusive prefix
        if (gid < NPROT) {
            rowptr[gid] = r;
            cursor[gid] = r;
            inv[gid] = 1.0f / (float)(v > 1 ? v : 1);
            if (gid == NPROT - 1) rowptr[NPROT] = r + v;
        }
    }
    grid.sync();

    // ---- phase D: CSR fill ----
    for (int e = gid; e < EPPI; e += 65536) {
        int d = dst[e];
        int p = atomicAdd(&cursor[d], 1);
        ssrc[p] = src[e];
    }
}

// ---------- layer-1 neighbor mean: gather Xb -> Am (bf16) ----------
// quarter-wave (16 lanes x bf16x8) per node, unroll-4 for load-level parallelism
__global__ void k_agg(const __bf16* __restrict__ Xb, const int* __restrict__ rowptr,
                      const int* __restrict__ ssrc, const float* __restrict__ inv,
                      __bf16* __restrict__ Am) {
    int wave = threadIdx.x >> 6, lane = threadIdx.x & 63;
    int q = lane >> 4, sl = lane & 15;
    int node = blockIdx.x * 16 + wave * 4 + q;
    if (node >= NPROT) return;
    int b0 = rowptr[node], b1 = rowptr[node + 1];
    float a[8];
#pragma unroll
    for (int e = 0; e < 8; e++) a[e] = 0.f;
    const __bf16* base = Xb + (size_t)sl * 8;
    int j = b0;
    for (; j + 4 <= b1; j += 4) {
        int s0 = ssrc[j], s1 = ssrc[j + 1], s2 = ssrc[j + 2], s3 = ssrc[j + 3];
        bf16x8 v0 = *(const bf16x8*)(base + (size_t)s0 * 128);
        bf16x8 v1 = *(const bf16x8*)(base + (size_t)s1 * 128);
        bf16x8 v2 = *(const bf16x8*)(base + (size_t)s2 * 128);
        bf16x8 v3 = *(const bf16x8*)(base + (size_t)s3 * 128);
#pragma unroll
        for (int e = 0; e < 8; e++)
            a[e] += ((float)v0[e] + (float)v1[e]) + ((float)v2[e] + (float)v3[e]);
    }
    for (; j < b1; j++) {
        int s = ssrc[j];
        bf16x8 v = *(const bf16x8*)(base + (size_t)s * 128);
#pragma unroll
        for (int e = 0; e < 8; e++) a[e] += (float)v[e];
    }
    float iv = inv[node];
    bf16x8 o;
#pragma unroll
    for (int e = 0; e < 8; e++) o[e] = (__bf16)(a[e] * iv);
    *(bf16x8*)(Am + (size_t)node * 128 + sl * 8) = o;
}

// ---------- GEMM z = [Am|Xb] @ Bw^T (+ab), relu, project onto P -> y[node][4] ----------
// 128 rows/block, 32 rows/wave. A fragments register-resident. B staged per 64-col
// chunk in fragment-major LDS layout -> all LDS traffic lane-linear, zero conflicts.
__global__ __launch_bounds__(256) void k_gemm(const __bf16* __restrict__ Am,
                                              const __bf16* __restrict__ Xb,
                                              const __bf16* __restrict__ Bw,
                                              const float* __restrict__ ab,
                                              const float* __restrict__ P,
                                              float* __restrict__ y) {
    __shared__ __bf16 Bs[2048 * 8];   // 32 KB
    int tid = threadIdx.x;
    int wave = tid >> 6, lane = tid & 63;
    int r = lane & 15, quad = lane >> 4;
    int row0 = blockIdx.x * 128 + wave * 32;

    // A fragments: kk 0..3 -> mean (Am), kk 4..7 -> own (Xb)
    bf16x8 afrag[2][8];
#pragma unroll
    for (int g = 0; g < 2; g++) {
        const __bf16* mp = Am + (size_t)(row0 + g * 16 + r) * 128 + quad * 8;
        const __bf16* op = Xb + (size_t)(row0 + g * 16 + r) * 128 + quad * 8;
#pragma unroll
        for (int kk = 0; kk < 4; kk++) {
            afrag[g][kk]     = *(const bf16x8*)(mp + kk * 32);
            afrag[g][4 + kk] = *(const bf16x8*)(op + kk * 32);
        }
    }

    float part[2][4][4] = {{{0.f}}};

    for (int chunk = 0; chunk < 4; chunk++) {
        if (chunk) __syncthreads();
#pragma unroll
        for (int jj = 0; jj < 8; jj++) {
            int g = jj * 256 + tid;
            int gr = g & 15, gq = (g >> 4) & 3;
            int gkk = (g >> 6) & 7;
            int gt = g >> 9;
            const __bf16* src = Bw + (size_t)(chunk * 64 + gt * 16 + gr) * 256 + gkk * 32 + gq * 8;
            *(bf16x8*)(Bs + (size_t)g * 8) = *(const bf16x8*)src;
        }
        __syncthreads();

        floatx4 acc[2][4];
#pragma unroll
        for (int g = 0; g < 2; g++)
#pragma unroll
            for (int t = 0; t < 4; t++) acc[g][t] = (floatx4){0.f, 0.f, 0.f, 0.f};
#pragma unroll
        for (int kk = 0; kk < 8; kk++) {
#pragma unroll
            for (int t = 0; t < 4; t++) {
                bf16x8 bf = *(const bf16x8*)(Bs + (size_t)((t * 8 + kk) * 64 + lane) * 8);
                acc[0][t] = __builtin_amdgcn_mfma_f32_16x16x32_bf16(afrag[0][kk], bf, acc[0][t], 0, 0, 0);
                acc[1][t] = __builtin_amdgcn_mfma_f32_16x16x32_bf16(afrag[1][kk], bf, acc[1][t], 0, 0, 0);
            }
        }

        // epilogue: h = relu(z + ab[col]); accumulate projection onto P
#pragma unroll
        for (int t = 0; t < 4; t++) {
            int col = chunk * 64 + t * 16 + r;
            float bias = ab[col];
            float4 pv = *(const float4*)(P + col * 4);
#pragma unroll
            for (int g = 0; g < 2; g++)
#pragma unroll
                for (int rr = 0; rr < 4; rr++) {
                    float h = acc[g][t][rr] + bias;
                    h = h > 0.f ? h : 0.f;
                    part[g][rr][0] += h * pv.x; part[g][rr][1] += h * pv.y;
                    part[g][rr][2] += h * pv.z; part[g][rr][3] += h * pv.w;
                }
        }
    }

    // reduce over the 16 col-lanes (r); store 32 rows per wave
#pragma unroll
    for (int m = 1; m < 16; m <<= 1)
#pragma unroll
        for (int g = 0; g < 2; g++)
#pragma unroll
            for (int rr = 0; rr < 4; rr++)
#pragma unroll
                for (int j = 0; j < 4; j++)
                    part[g][rr][j] += __shfl_xor(part[g][rr][j], m, 64);
    if (r == 0) {
#pragma unroll
        for (int g = 0; g < 2; g++)
#pragma unroll
            for (int rr = 0; rr < 4; rr++) {
                int row = row0 + g * 16 + quad * 4 + rr;
                float4 o;
                o.x = part[g][rr][0]; o.y = part[g][rr][1];
                o.z = part[g][rr][2]; o.w = part[g][rr][3];
                *(float4*)(y + (size_t)row * 4) = o;
            }
    }
}

// ---------- head: per masked node, CSR-sum scalar projections ----------
__global__ void k_head(const int* __restrict__ mask, const int* __restrict__ rowptr,
                       const int* __restrict__ ssrc, const float* __restrict__ inv,
                       const float* __restrict__ y, const float* __restrict__ biasC,
                       float* __restrict__ out) {
    int tid = blockIdx.x * 256 + threadIdx.x;
    int p = tid >> 1, side = tid & 1;
    float res = 0.f;
    if (p < NPAIR) {
        int node = mask[p * 2 + side];
        int b0 = rowptr[node], b1 = rowptr[node + 1];
        float s = 0.f;
        for (int j = b0; j < b1; j++) s += y[(size_t)ssrc[j] * 4 + side];
        res = s * inv[node] + y[(size_t)node * 4 + 2 + side];
    }
    float other = __shfl_xor(res, 1, 64);
    if (p < NPAIR && side == 0) {
        float z = res + other + *biasC;
        out[p] = 1.f / (1.f + expf(-z));
    }
}

extern "C" void kernel_launch(void* const* d_in, const int* in_sizes, int n_in,
                              void* d_out, int out_size, void* d_ws, size_t ws_size,
                              hipStream_t stream) {
    const float* x_protein = (const float*)d_in[0];
    const float* a_ppi_Wl  = (const float*)d_in[11];
    const float* a_ppi_b   = (const float*)d_in[12];
    const float* a_ppi_Wr  = (const float*)d_in[13];
    const float* b_ppi_Wl  = (const float*)d_in[23];
    const float* b_ppi_b   = (const float*)d_in[24];
    const float* b_ppi_Wr  = (const float*)d_in[25];
    const float* lin_W     = (const float*)d_in[26];
    const float* lin_b     = (const float*)d_in[27];
    const int* ppi_src     = (const int*)d_in[34];
    const int* ppi_dst     = (const int*)d_in[35];
    const int* mask        = (const int*)d_in[36];
    float* out = (float*)d_out;

    char* ws = (char*)d_ws;
    size_t o = 0;
    auto alloc = [&](size_t n) -> char* {
        char* r = ws + o;
        o = (o + n + 511) & ~(size_t)511;
        return r;
    };
    int*    cnt      = (int*)alloc((size_t)NPROT * 4);
    int*    rowptr   = (int*)alloc((size_t)(NPROT + 1) * 4);
    int*    cursor   = (int*)alloc((size_t)NPROT * 4);
    int*    blocksum = (int*)alloc(256 * 4);
    float*  inv      = (float*)alloc((size_t)NPROT * 4);
    int*    ssrc     = (int*)alloc((size_t)EPPI * 4);
    __bf16* Xb       = (__bf16*)alloc((size_t)NPROT_PAD * 128 * 2);
    __bf16* Am       = (__bf16*)alloc((size_t)NPROT_PAD * 128 * 2);
    __bf16* Bw       = (__bf16*)alloc(256 * 256 * 2);
    float*  P        = (float*)alloc(256 * 4 * 4);
    float*  biasC    = (float*)alloc(4);
    float*  y        = (float*)alloc((size_t)NPROT_PAD * 4 * 4);
    (void)ws_size;

    void* args[] = {
        (void*)&x_protein, (void*)&a_ppi_Wl, (void*)&a_ppi_Wr,
        (void*)&lin_W, (void*)&lin_b, (void*)&b_ppi_Wl, (void*)&b_ppi_Wr, (void*)&b_ppi_b,
        (void*)&ppi_src, (void*)&ppi_dst,
        (void*)&Xb, (void*)&Bw, (void*)&P, (void*)&biasC,
        (void*)&cnt, (void*)&rowptr, (void*)&cursor, (void*)&inv,
        (void*)&blocksum, (void*)&ssrc,
    };
    hipLaunchCooperativeKernel((void*)k_build, dim3(256), dim3(256), args, 0, stream);

    k_agg<<<(NPROT + 15) / 16, 256, 0, stream>>>(Xb, rowptr, ssrc, inv, Am);
    k_gemm<<<(NPROT_PAD + 127) / 128, 256, 0, stream>>>(Am, Xb, Bw, a_ppi_b, P, y);
    k_head<<<(2 * NPAIR + 255) / 256, 256, 0, stream>>>(mask, rowptr, ssrc, inv, y, biasC, out);
}

// Round 7
// 262.478 us; speedup vs baseline: 1.5579x; 1.5579x over previous
//
#include <hip/hip_runtime.h>
#include <math.h>

#define NPROT 50000
#define NPROT_PAD 50048
#define EPPI 500000
#define NPAIR 4096

typedef __attribute__((ext_vector_type(8))) __bf16 bf16x8;
typedef __attribute__((ext_vector_type(4))) __bf16 bf16x4;
typedef __attribute__((ext_vector_type(4))) float floatx4;

// ---------- CSR build ----------
__global__ void k_hist(const int* __restrict__ dst, int* __restrict__ cnt) {
    int e = blockIdx.x * 256 + threadIdx.x;
    if (e < EPPI) atomicAdd(&cnt[dst[e]], 1);
}

__global__ void k_scan1(const int* __restrict__ cnt, int* __restrict__ rowptr,
                        int* __restrict__ blocksum) {
    __shared__ int sd[1024];
    int t = threadIdx.x;
    int i = blockIdx.x * 1024 + t;
    int v = (i < NPROT) ? cnt[i] : 0;
    sd[t] = v;
    __syncthreads();
    int x = v;
    for (int off = 1; off < 1024; off <<= 1) {
        int add = (t >= off) ? sd[t - off] : 0;
        __syncthreads();
        x += add;
        sd[t] = x;
        __syncthreads();
    }
    if (i < NPROT) rowptr[i] = x - v;   // block-local exclusive
    if (t == 1023) blocksum[blockIdx.x] = x;
}

// scan3 with fused block-prefix: wave 0 reduces blocksum[0..bid)
__global__ void k_scan3(const int* __restrict__ cnt, int* __restrict__ rowptr,
                        int* __restrict__ cursor, float* __restrict__ inv,
                        const int* __restrict__ blocksum, int nb) {
    __shared__ int spref;
    int t = threadIdx.x;
    if (t < 64) {
        int v = (t < blockIdx.x && t < nb) ? blocksum[t] : 0;
#pragma unroll
        for (int m = 1; m < 64; m <<= 1) v += __shfl_xor(v, m, 64);
        if (t == 0) spref = v;
    }
    __syncthreads();
    int i = blockIdx.x * 1024 + t;
    if (i < NPROT) {
        int r = rowptr[i] + spref;
        rowptr[i] = r;
        cursor[i] = r;
        int c = cnt[i];
        inv[i] = 1.0f / (float)(c > 1 ? c : 1);
        if (i == NPROT - 1) rowptr[NPROT] = r + c;
    }
}

__global__ void k_fill(const int* __restrict__ src, const int* __restrict__ dst,
                       int* __restrict__ cursor, int* __restrict__ ssrc) {
    int e = blockIdx.x * 256 + threadIdx.x;
    if (e < EPPI) {
        int d = dst[e];
        int p = atomicAdd(&cursor[d], 1);
        ssrc[p] = src[e];
    }
}

// ---------- fused prep: x->bf16 table Xb, Bw build, P/biasC, zero cnt ----------
__global__ void k_prep(const float* __restrict__ x,
                       const float* __restrict__ Wl, const float* __restrict__ Wr,
                       const float* __restrict__ linW, const float* __restrict__ linb,
                       const float* __restrict__ bWl, const float* __restrict__ bWr,
                       const float* __restrict__ bb,
                       __bf16* __restrict__ Xb, __bf16* __restrict__ Bw,
                       float* __restrict__ P, float* __restrict__ biasC,
                       int* __restrict__ cnt) {
    int b = blockIdx.x, t = threadIdx.x;
    if (b < 6250) {
        int i = b * 256 + t;              // float4 index over 50000*32
        int row = i >> 5, k4 = (i & 31) << 2;
        float4 v = *(const float4*)(x + (size_t)row * 128 + k4);
        bf16x4 o; o[0] = (__bf16)v.x; o[1] = (__bf16)v.y; o[2] = (__bf16)v.z; o[3] = (__bf16)v.w;
        *(bf16x4*)(Xb + (size_t)row * 128 + k4) = o;
    } else if (b < 6506) {
        // Bw[h][k]: k<128 -> aWl, else aWr  (bf16)
        int idx = (b - 6250) * 256 + t;   // 65536
        int h = idx >> 8, k = idx & 255;
        float v = (k < 128) ? Wl[h * 128 + k] : Wr[h * 128 + (k - 128)];
        Bw[idx] = (__bf16)v;
    } else if (b == 6506) {
        int h = t;  // 256
        float v1 = 0, v2 = 0, u1 = 0, u2 = 0;
        for (int f = 0; f < 128; f++) {
            float w1 = linW[f], w2 = linW[128 + f];
            float wl = bWl[f * 256 + h], wr = bWr[f * 256 + h];
            v1 += w1 * wl; v2 += w2 * wl; u1 += w1 * wr; u2 += w2 * wr;
        }
        P[h * 4 + 0] = v1; P[h * 4 + 1] = v2; P[h * 4 + 2] = u1; P[h * 4 + 3] = u2;
        if (h == 0) {
            float c = linb[0];
            for (int f = 0; f < 128; f++) c += (linW[f] + linW[128 + f]) * bb[f];
            *biasC = c;
        }
    } else {
        int i = (b - 6507) * 256 + t;
        if (i < NPROT) cnt[i] = 0;
    }
}

// ---------- layer-1 neighbor mean: gather Xb -> Am (bf16) ----------
// quarter-wave (16 lanes x bf16x8) per node, unroll-8 for deep load pipelining
__global__ void k_agg(const __bf16* __restrict__ Xb, const int* __restrict__ rowptr,
                      const int* __restrict__ ssrc, const float* __restrict__ inv,
                      __bf16* __restrict__ Am) {
    int wave = threadIdx.x >> 6, lane = threadIdx.x & 63;
    int q = lane >> 4, sl = lane & 15;
    int node = blockIdx.x * 16 + wave * 4 + q;
    if (node >= NPROT) return;
    int b0 = rowptr[node], b1 = rowptr[node + 1];
    float a[8];
#pragma unroll
    for (int e = 0; e < 8; e++) a[e] = 0.f;
    const __bf16* base = Xb + (size_t)sl * 8;
    int j = b0;
    for (; j + 8 <= b1; j += 8) {
        int s[8];
#pragma unroll
        for (int u = 0; u < 8; u++) s[u] = ssrc[j + u];
        bf16x8 v[8];
#pragma unroll
        for (int u = 0; u < 8; u++) v[u] = *(const bf16x8*)(base + (size_t)s[u] * 128);
#pragma unroll
        for (int e = 0; e < 8; e++) {
            float t0 = ((float)v[0][e] + (float)v[1][e]) + ((float)v[2][e] + (float)v[3][e]);
            float t1 = ((float)v[4][e] + (float)v[5][e]) + ((float)v[6][e] + (float)v[7][e]);
            a[e] += t0 + t1;
        }
    }
    if (j + 4 <= b1) {
        int s0 = ssrc[j], s1 = ssrc[j + 1], s2 = ssrc[j + 2], s3 = ssrc[j + 3];
        bf16x8 v0 = *(const bf16x8*)(base + (size_t)s0 * 128);
        bf16x8 v1 = *(const bf16x8*)(base + (size_t)s1 * 128);
        bf16x8 v2 = *(const bf16x8*)(base + (size_t)s2 * 128);
        bf16x8 v3 = *(const bf16x8*)(base + (size_t)s3 * 128);
#pragma unroll
        for (int e = 0; e < 8; e++)
            a[e] += ((float)v0[e] + (float)v1[e]) + ((float)v2[e] + (float)v3[e]);
        j += 4;
    }
    for (; j < b1; j++) {
        int s = ssrc[j];
        bf16x8 v = *(const bf16x8*)(base + (size_t)s * 128);
#pragma unroll
        for (int e = 0; e < 8; e++) a[e] += (float)v[e];
    }
    float iv = inv[node];
    bf16x8 o;
#pragma unroll
    for (int e = 0; e < 8; e++) o[e] = (__bf16)(a[e] * iv);
    *(bf16x8*)(Am + (size_t)node * 128 + sl * 8) = o;
}

// ---------- GEMM z = [Am|Xb] @ Bw^T (+ab), relu, project onto P -> y[node][4] ----------
// 128 rows/block, 32 rows/wave. A fragments register-resident. B staged per 64-col
// chunk in fragment-major LDS layout -> all LDS traffic lane-linear, zero conflicts.
__global__ __launch_bounds__(256) void k_gemm(const __bf16* __restrict__ Am,
                                              const __bf16* __restrict__ Xb,
                                              const __bf16* __restrict__ Bw,
                                              const float* __restrict__ ab,
                                              const float* __restrict__ P,
                                              float* __restrict__ y) {
    __shared__ __bf16 Bs[2048 * 8];   // 32 KB
    int tid = threadIdx.x;
    int wave = tid >> 6, lane = tid & 63;
    int r = lane & 15, quad = lane >> 4;
    int row0 = blockIdx.x * 128 + wave * 32;

    // A fragments: kk 0..3 -> mean (Am), kk 4..7 -> own (Xb)
    bf16x8 afrag[2][8];
#pragma unroll
    for (int g = 0; g < 2; g++) {
        const __bf16* mp = Am + (size_t)(row0 + g * 16 + r) * 128 + quad * 8;
        const __bf16* op = Xb + (size_t)(row0 + g * 16 + r) * 128 + quad * 8;
#pragma unroll
        for (int kk = 0; kk < 4; kk++) {
            afrag[g][kk]     = *(const bf16x8*)(mp + kk * 32);
            afrag[g][4 + kk] = *(const bf16x8*)(op + kk * 32);
        }
    }

    float part[2][4][4] = {{{0.f}}};

    for (int chunk = 0; chunk < 4; chunk++) {
        if (chunk) __syncthreads();
#pragma unroll
        for (int jj = 0; jj < 8; jj++) {
            int g = jj * 256 + tid;
            int gr = g & 15, gq = (g >> 4) & 3;
            int gkk = (g >> 6) & 7;
            int gt = g >> 9;
            const __bf16* src = Bw + (size_t)(chunk * 64 + gt * 16 + gr) * 256 + gkk * 32 + gq * 8;
            *(bf16x8*)(Bs + (size_t)g * 8) = *(const bf16x8*)src;
        }
        __syncthreads();

        floatx4 acc[2][4];
#pragma unroll
        for (int g = 0; g < 2; g++)
#pragma unroll
            for (int t = 0; t < 4; t++) acc[g][t] = (floatx4){0.f, 0.f, 0.f, 0.f};
#pragma unroll
        for (int kk = 0; kk < 8; kk++) {
#pragma unroll
            for (int t = 0; t < 4; t++) {
                bf16x8 bf = *(const bf16x8*)(Bs + (size_t)((t * 8 + kk) * 64 + lane) * 8);
                acc[0][t] = __builtin_amdgcn_mfma_f32_16x16x32_bf16(afrag[0][kk], bf, acc[0][t], 0, 0, 0);
                acc[1][t] = __builtin_amdgcn_mfma_f32_16x16x32_bf16(afrag[1][kk], bf, acc[1][t], 0, 0, 0);
            }
        }

        // epilogue: h = relu(z + ab[col]); accumulate projection onto P
#pragma unroll
        for (int t = 0; t < 4; t++) {
            int col = chunk * 64 + t * 16 + r;
            float bias = ab[col];
            float4 pv = *(const float4*)(P + col * 4);
#pragma unroll
            for (int g = 0; g < 2; g++)
#pragma unroll
                for (int rr = 0; rr < 4; rr++) {
                    float h = acc[g][t][rr] + bias;
                    h = h > 0.f ? h : 0.f;
                    part[g][rr][0] += h * pv.x; part[g][rr][1] += h * pv.y;
                    part[g][rr][2] += h * pv.z; part[g][rr][3] += h * pv.w;
                }
        }
    }

    // reduce over the 16 col-lanes (r); store 32 rows per wave
#pragma unroll
    for (int m = 1; m < 16; m <<= 1)
#pragma unroll
        for (int g = 0; g < 2; g++)
#pragma unroll
            for (int rr = 0; rr < 4; rr++)
#pragma unroll
                for (int j = 0; j < 4; j++)
                    part[g][rr][j] += __shfl_xor(part[g][rr][j], m, 64);
    if (r == 0) {
#pragma unroll
        for (int g = 0; g < 2; g++)
#pragma unroll
            for (int rr = 0; rr < 4; rr++) {
                int row = row0 + g * 16 + quad * 4 + rr;
                float4 o;
                o.x = part[g][rr][0]; o.y = part[g][rr][1];
                o.z = part[g][rr][2]; o.w = part[g][rr][3];
                *(float4*)(y + (size_t)row * 4) = o;
            }
    }
}

// ---------- head: per masked node, CSR-sum scalar projections ----------
__global__ void k_head(const int* __restrict__ mask, const int* __restrict__ rowptr,
                       const int* __restrict__ ssrc, const float* __restrict__ inv,
                       const float* __restrict__ y, const float* __restrict__ biasC,
                       float* __restrict__ out) {
    int tid = blockIdx.x * 256 + threadIdx.x;
    int p = tid >> 1, side = tid & 1;
    float res = 0.f;
    if (p < NPAIR) {
        int node = mask[p * 2 + side];
        int b0 = rowptr[node], b1 = rowptr[node + 1];
        float s = 0.f;
        for (int j = b0; j < b1; j++) s += y[(size_t)ssrc[j] * 4 + side];
        res = s * inv[node] + y[(size_t)node * 4 + 2 + side];
    }
    float other = __shfl_xor(res, 1, 64);
    if (p < NPAIR && side == 0) {
        float z = res + other + *biasC;
        out[p] = 1.f / (1.f + expf(-z));
    }
}

extern "C" void kernel_launch(void* const* d_in, const int* in_sizes, int n_in,
                              void* d_out, int out_size, void* d_ws, size_t ws_size,
                              hipStream_t stream) {
    const float* x_protein = (const float*)d_in[0];
    const float* a_ppi_Wl  = (const float*)d_in[11];
    const float* a_ppi_b   = (const float*)d_in[12];
    const float* a_ppi_Wr  = (const float*)d_in[13];
    const float* b_ppi_Wl  = (const float*)d_in[23];
    const float* b_ppi_b   = (const float*)d_in[24];
    const float* b_ppi_Wr  = (const float*)d_in[25];
    const float* lin_W     = (const float*)d_in[26];
    const float* lin_b     = (const float*)d_in[27];
    const int* ppi_src     = (const int*)d_in[34];
    const int* ppi_dst     = (const int*)d_in[35];
    const int* mask        = (const int*)d_in[36];
    float* out = (float*)d_out;

    char* ws = (char*)d_ws;
    size_t o = 0;
    auto alloc = [&](size_t n) -> char* {
        char* r = ws + o;
        o = (o + n + 511) & ~(size_t)511;
        return r;
    };
    int*    cnt      = (int*)alloc((size_t)NPROT * 4);
    int*    rowptr   = (int*)alloc((size_t)(NPROT + 1) * 4);
    int*    cursor   = (int*)alloc((size_t)NPROT * 4);
    int*    blocksum = (int*)alloc(64 * 4);
    float*  inv      = (float*)alloc((size_t)NPROT * 4);
    int*    ssrc     = (int*)alloc((size_t)EPPI * 4);
    __bf16* Xb       = (__bf16*)alloc((size_t)NPROT_PAD * 128 * 2);
    __bf16* Am       = (__bf16*)alloc((size_t)NPROT_PAD * 128 * 2);
    __bf16* Bw       = (__bf16*)alloc(256 * 256 * 2);
    float*  P        = (float*)alloc(256 * 4 * 4);
    float*  biasC    = (float*)alloc(4);
    float*  y        = (float*)alloc((size_t)NPROT_PAD * 4 * 4);
    (void)ws_size;

    int nb = (NPROT + 1023) / 1024;  // 49

    k_prep<<<6703, 256, 0, stream>>>(x_protein, a_ppi_Wl, a_ppi_Wr, lin_W, lin_b,
                                     b_ppi_Wl, b_ppi_Wr, b_ppi_b,
                                     Xb, Bw, P, biasC, cnt);
    k_hist<<<(EPPI + 255) / 256, 256, 0, stream>>>(ppi_dst, cnt);
    k_scan1<<<nb, 1024, 0, stream>>>(cnt, rowptr, blocksum);
    k_scan3<<<nb, 1024, 0, stream>>>(cnt, rowptr, cursor, inv, blocksum, nb);
    k_fill<<<(EPPI + 255) / 256, 256, 0, stream>>>(ppi_src, ppi_dst, cursor, ssrc);
    k_agg<<<(NPROT + 15) / 16, 256, 0, stream>>>(Xb, rowptr, ssrc, inv, Am);
    k_gemm<<<(NPROT_PAD + 127) / 128, 256, 0, stream>>>(Am, Xb, Bw, a_ppi_b, P, y);
    k_head<<<(2 * NPAIR + 255) / 256, 256, 0, stream>>>(mask, rowptr, ssrc, inv, y, biasC, out);
}

// Round 8
// 242.601 us; speedup vs baseline: 1.6855x; 1.0819x over previous
//
#include <hip/hip_runtime.h>
#include <math.h>

#define NPROT 50000
#define NPROT_PAD 50048
#define EPPI 500000
#define NPAIR 4096

typedef __attribute__((ext_vector_type(8))) __bf16 bf16x8;
typedef __attribute__((ext_vector_type(4))) __bf16 bf16x4;
typedef __attribute__((ext_vector_type(4))) float floatx4;

// ---------- prep: Xb bf16 cast, Bw pack, P/biasC, head[]=-1 ----------
__global__ void k_prep(const float* __restrict__ x,
                       const float* __restrict__ Wl, const float* __restrict__ Wr,
                       const float* __restrict__ linW, const float* __restrict__ linb,
                       const float* __restrict__ bWl, const float* __restrict__ bWr,
                       const float* __restrict__ bb,
                       __bf16* __restrict__ Xb, __bf16* __restrict__ Bw,
                       float* __restrict__ P, float* __restrict__ biasC,
                       int* __restrict__ head) {
    int b = blockIdx.x, t = threadIdx.x;
    if (b < 6250) {
        int i = b * 256 + t;              // float4 index over 50000*32
        int row = i >> 5, k4 = (i & 31) << 2;
        float4 v = *(const float4*)(x + (size_t)row * 128 + k4);
        bf16x4 o; o[0] = (__bf16)v.x; o[1] = (__bf16)v.y; o[2] = (__bf16)v.z; o[3] = (__bf16)v.w;
        *(bf16x4*)(Xb + (size_t)row * 128 + k4) = o;
    } else if (b < 6506) {
        // Bw[h][k]: k<128 -> aWl, else aWr  (bf16)
        int idx = (b - 6250) * 256 + t;   // 65536
        int h = idx >> 8, k = idx & 255;
        float v = (k < 128) ? Wl[h * 128 + k] : Wr[h * 128 + (k - 128)];
        Bw[idx] = (__bf16)v;
    } else if (b == 6506) {
        int h = t;  // 256
        float v1 = 0, v2 = 0, u1 = 0, u2 = 0;
        for (int f = 0; f < 128; f++) {
            float w1 = linW[f], w2 = linW[128 + f];
            float wl = bWl[f * 256 + h], wr = bWr[f * 256 + h];
            v1 += w1 * wl; v2 += w2 * wl; u1 += w1 * wr; u2 += w2 * wr;
        }
        P[h * 4 + 0] = v1; P[h * 4 + 1] = v2; P[h * 4 + 2] = u1; P[h * 4 + 3] = u2;
        if (h == 0) {
            float c = linb[0];
            for (int f = 0; f < 128; f++) c += (linW[f] + linW[128 + f]) * bb[f];
            *biasC = c;
        }
    } else {
        int i = (b - 6507) * 256 + t;
        if (i < NPROT) head[i] = -1;
    }
}

// ---------- adjacency: single-pass linked list ----------
__global__ void k_link(const int* __restrict__ src, const int* __restrict__ dst,
                       int* __restrict__ head, int2* __restrict__ elist) {
    int e = blockIdx.x * 256 + threadIdx.x;
    if (e < EPPI) {
        int d = dst[e];
        int prev = atomicExch(&head[d], e);
        elist[e] = make_int2(src[e], prev);
    }
}

// ---------- layer-1 neighbor mean: chain-walk gather Xb -> Am (bf16), inv ----------
// quarter-wave (16 lanes x bf16x8) per node; chain hop = one broadcast 8B load
__global__ void k_agg(const __bf16* __restrict__ Xb, const int* __restrict__ head,
                      const int2* __restrict__ elist, float* __restrict__ inv,
                      __bf16* __restrict__ Am) {
    int wave = threadIdx.x >> 6, lane = threadIdx.x & 63;
    int q = lane >> 4, sl = lane & 15;
    int node = blockIdx.x * 16 + wave * 4 + q;
    if (node >= NPROT) return;
    float a[8];
#pragma unroll
    for (int e8 = 0; e8 < 8; e8++) a[e8] = 0.f;
    const __bf16* base = Xb + (size_t)sl * 8;
    int e = head[node];
    int c = 0;
    while (e >= 0) {
        int2 el = elist[e];
        bf16x8 v = *(const bf16x8*)(base + (size_t)el.x * 128);
#pragma unroll
        for (int e8 = 0; e8 < 8; e8++) a[e8] += (float)v[e8];
        c++;
        e = el.y;
    }
    float iv = 1.0f / (float)(c > 1 ? c : 1);
    if (sl == 0 && q == 0) { /* one lane per node writes inv */ }
    if (sl == 0) inv[node] = iv;   // redundant across q? no: q selects node; sl==0 unique per node
    bf16x8 o;
#pragma unroll
    for (int e8 = 0; e8 < 8; e8++) o[e8] = (__bf16)(a[e8] * iv);
    *(bf16x8*)(Am + (size_t)node * 128 + sl * 8) = o;
}

// ---------- GEMM z = [Am|Xb] @ Bw^T (+ab), relu, project onto P -> y[node][4] ----------
// 128 rows/block, 32 rows/wave. A fragments register-resident. B staged per 64-col
// chunk in fragment-major LDS layout -> all LDS traffic lane-linear, zero conflicts.
__global__ __launch_bounds__(256) void k_gemm(const __bf16* __restrict__ Am,
                                              const __bf16* __restrict__ Xb,
                                              const __bf16* __restrict__ Bw,
                                              const float* __restrict__ ab,
                                              const float* __restrict__ P,
                                              float* __restrict__ y) {
    __shared__ __bf16 Bs[2048 * 8];   // 32 KB
    int tid = threadIdx.x;
    int wave = tid >> 6, lane = tid & 63;
    int r = lane & 15, quad = lane >> 4;
    int row0 = blockIdx.x * 128 + wave * 32;

    // A fragments: kk 0..3 -> mean (Am), kk 4..7 -> own (Xb)
    bf16x8 afrag[2][8];
#pragma unroll
    for (int g = 0; g < 2; g++) {
        const __bf16* mp = Am + (size_t)(row0 + g * 16 + r) * 128 + quad * 8;
        const __bf16* op = Xb + (size_t)(row0 + g * 16 + r) * 128 + quad * 8;
#pragma unroll
        for (int kk = 0; kk < 4; kk++) {
            afrag[g][kk]     = *(const bf16x8*)(mp + kk * 32);
            afrag[g][4 + kk] = *(const bf16x8*)(op + kk * 32);
        }
    }

    float part[2][4][4] = {{{0.f}}};

    for (int chunk = 0; chunk < 4; chunk++) {
        if (chunk) __syncthreads();
#pragma unroll
        for (int jj = 0; jj < 8; jj++) {
            int g = jj * 256 + tid;
            int gr = g & 15, gq = (g >> 4) & 3;
            int gkk = (g >> 6) & 7;
            int gt = g >> 9;
            const __bf16* src = Bw + (size_t)(chunk * 64 + gt * 16 + gr) * 256 + gkk * 32 + gq * 8;
            *(bf16x8*)(Bs + (size_t)g * 8) = *(const bf16x8*)src;
        }
        __syncthreads();

        floatx4 acc[2][4];
#pragma unroll
        for (int g = 0; g < 2; g++)
#pragma unroll
            for (int t = 0; t < 4; t++) acc[g][t] = (floatx4){0.f, 0.f, 0.f, 0.f};
#pragma unroll
        for (int kk = 0; kk < 8; kk++) {
#pragma unroll
            for (int t = 0; t < 4; t++) {
                bf16x8 bf = *(const bf16x8*)(Bs + (size_t)((t * 8 + kk) * 64 + lane) * 8);
                acc[0][t] = __builtin_amdgcn_mfma_f32_16x16x32_bf16(afrag[0][kk], bf, acc[0][t], 0, 0, 0);
                acc[1][t] = __builtin_amdgcn_mfma_f32_16x16x32_bf16(afrag[1][kk], bf, acc[1][t], 0, 0, 0);
            }
        }

        // epilogue: h = relu(z + ab[col]); accumulate projection onto P
#pragma unroll
        for (int t = 0; t < 4; t++) {
            int col = chunk * 64 + t * 16 + r;
            float bias = ab[col];
            float4 pv = *(const float4*)(P + col * 4);
#pragma unroll
            for (int g = 0; g < 2; g++)
#pragma unroll
                for (int rr = 0; rr < 4; rr++) {
                    float h = acc[g][t][rr] + bias;
                    h = h > 0.f ? h : 0.f;
                    part[g][rr][0] += h * pv.x; part[g][rr][1] += h * pv.y;
                    part[g][rr][2] += h * pv.z; part[g][rr][3] += h * pv.w;
                }
        }
    }

    // reduce over the 16 col-lanes (r); store 32 rows per wave
#pragma unroll
    for (int m = 1; m < 16; m <<= 1)
#pragma unroll
        for (int g = 0; g < 2; g++)
#pragma unroll
            for (int rr = 0; rr < 4; rr++)
#pragma unroll
                for (int j = 0; j < 4; j++)
                    part[g][rr][j] += __shfl_xor(part[g][rr][j], m, 64);
    if (r == 0) {
#pragma unroll
        for (int g = 0; g < 2; g++)
#pragma unroll
            for (int rr = 0; rr < 4; rr++) {
                int row = row0 + g * 16 + quad * 4 + rr;
                float4 o;
                o.x = part[g][rr][0]; o.y = part[g][rr][1];
                o.z = part[g][rr][2]; o.w = part[g][rr][3];
                *(float4*)(y + (size_t)row * 4) = o;
            }
    }
}

// ---------- head: per masked node, chain-walk sum of scalar projections ----------
__global__ void k_head(const int* __restrict__ mask, const int* __restrict__ head,
                       const int2* __restrict__ elist, const float* __restrict__ y,
                       const float* __restrict__ biasC, float* __restrict__ out) {
    int tid = blockIdx.x * 256 + threadIdx.x;
    int p = tid >> 1, side = tid & 1;
    float res = 0.f;
    if (p < NPAIR) {
        int node = mask[p * 2 + side];
        int e = head[node];
        float s = 0.f;
        int c = 0;
        while (e >= 0) {
            int2 el = elist[e];
            s += y[(size_t)el.x * 4 + side];
            c++;
            e = el.y;
        }
        float iv = 1.0f / (float)(c > 1 ? c : 1);
        res = s * iv + y[(size_t)node * 4 + 2 + side];
    }
    float other = __shfl_xor(res, 1, 64);
    if (p < NPAIR && side == 0) {
        float z = res + other + *biasC;
        out[p] = 1.f / (1.f + expf(-z));
    }
}

extern "C" void kernel_launch(void* const* d_in, const int* in_sizes, int n_in,
                              void* d_out, int out_size, void* d_ws, size_t ws_size,
                              hipStream_t stream) {
    const float* x_protein = (const float*)d_in[0];
    const float* a_ppi_Wl  = (const float*)d_in[11];
    const float* a_ppi_b   = (const float*)d_in[12];
    const float* a_ppi_Wr  = (const float*)d_in[13];
    const float* b_ppi_Wl  = (const float*)d_in[23];
    const float* b_ppi_b   = (const float*)d_in[24];
    const float* b_ppi_Wr  = (const float*)d_in[25];
    const float* lin_W     = (const float*)d_in[26];
    const float* lin_b     = (const float*)d_in[27];
    const int* ppi_src     = (const int*)d_in[34];
    const int* ppi_dst     = (const int*)d_in[35];
    const int* mask        = (const int*)d_in[36];
    float* out = (float*)d_out;

    char* ws = (char*)d_ws;
    size_t o = 0;
    auto alloc = [&](size_t n) -> char* {
        char* r = ws + o;
        o = (o + n + 511) & ~(size_t)511;
        return r;
    };
    int*    head   = (int*)alloc((size_t)NPROT * 4);
    int2*   elist  = (int2*)alloc((size_t)EPPI * 8);
    float*  inv    = (float*)alloc((size_t)NPROT * 4);
    __bf16* Xb     = (__bf16*)alloc((size_t)NPROT_PAD * 128 * 2);
    __bf16* Am     = (__bf16*)alloc((size_t)NPROT_PAD * 128 * 2);
    __bf16* Bw     = (__bf16*)alloc(256 * 256 * 2);
    float*  P      = (float*)alloc(256 * 4 * 4);
    float*  biasC  = (float*)alloc(4);
    float*  y      = (float*)alloc((size_t)NPROT_PAD * 4 * 4);
    (void)ws_size;

    k_prep<<<6703, 256, 0, stream>>>(x_protein, a_ppi_Wl, a_ppi_Wr, lin_W, lin_b,
                                     b_ppi_Wl, b_ppi_Wr, b_ppi_b,
                                     Xb, Bw, P, biasC, head);
    k_link<<<(EPPI + 255) / 256, 256, 0, stream>>>(ppi_src, ppi_dst, head, elist);
    k_agg<<<(NPROT + 15) / 16, 256, 0, stream>>>(Xb, head, elist, inv, Am);
    k_gemm<<<(NPROT_PAD + 127) / 128, 256, 0, stream>>>(Am, Xb, Bw, a_ppi_b, P, y);
    k_head<<<(2 * NPAIR + 255) / 256, 256, 0, stream>>>(mask, head, elist, y, biasC, out);
}

// Round 9
// 241.539 us; speedup vs baseline: 1.6929x; 1.0044x over previous
//
#include <hip/hip_runtime.h>
#include <math.h>

#define NPROT 50000
#define NPROT_PAD 50048
#define EPPI 500000
#define NPAIR 4096

typedef __attribute__((ext_vector_type(8))) __bf16 bf16x8;
typedef __attribute__((ext_vector_type(4))) __bf16 bf16x4;
typedef __attribute__((ext_vector_type(4))) float floatx4;

// ---------- prep: Xb bf16 cast, Bw pack, P/biasC (parallel), head[]=-1 ----------
__global__ void k_prep(const float* __restrict__ x,
                       const float* __restrict__ Wl, const float* __restrict__ Wr,
                       const float* __restrict__ linW, const float* __restrict__ linb,
                       const float* __restrict__ bWl, const float* __restrict__ bWr,
                       const float* __restrict__ bb,
                       __bf16* __restrict__ Xb, __bf16* __restrict__ Bw,
                       float* __restrict__ P, float* __restrict__ biasC,
                       int* __restrict__ head) {
    __shared__ float sP[10];
    int b = blockIdx.x, t = threadIdx.x;
    if (b < 6250) {
        int i = b * 256 + t;              // float4 index over 50000*32
        int row = i >> 5, k4 = (i & 31) << 2;
        float4 v = *(const float4*)(x + (size_t)row * 128 + k4);
        bf16x4 o; o[0] = (__bf16)v.x; o[1] = (__bf16)v.y; o[2] = (__bf16)v.z; o[3] = (__bf16)v.w;
        *(bf16x4*)(Xb + (size_t)row * 128 + k4) = o;
    } else if (b < 6506) {
        // Bw[h][k]: k<128 -> aWl, else aWr  (bf16)
        int idx = (b - 6250) * 256 + t;   // 65536
        int h = idx >> 8, k = idx & 255;
        float v = (k < 128) ? Wl[h * 128 + k] : Wr[h * 128 + (k - 128)];
        Bw[idx] = (__bf16)v;
    } else if (b < 6762) {
        // P[h][0..3] via 128-wide parallel dot; block handles output column h
        int h = b - 6506;
        int lane = t & 63, wave = t >> 6;
        float v1 = 0, v2 = 0, u1 = 0, u2 = 0, c = 0;
        if (t < 128) {
            float w1 = linW[t], w2 = linW[128 + t];
            float wl = bWl[t * 256 + h], wr = bWr[t * 256 + h];
            v1 = w1 * wl; v2 = w2 * wl; u1 = w1 * wr; u2 = w2 * wr;
            if (h == 0) c = (w1 + w2) * bb[t];
        }
#pragma unroll
        for (int m = 1; m < 64; m <<= 1) {
            v1 += __shfl_xor(v1, m, 64); v2 += __shfl_xor(v2, m, 64);
            u1 += __shfl_xor(u1, m, 64); u2 += __shfl_xor(u2, m, 64);
            c  += __shfl_xor(c, m, 64);
        }
        if (lane == 0 && wave < 2) {
            sP[wave * 5 + 0] = v1; sP[wave * 5 + 1] = v2;
            sP[wave * 5 + 2] = u1; sP[wave * 5 + 3] = u2;
            sP[wave * 5 + 4] = c;
        }
        __syncthreads();
        if (t == 0) {
            P[h * 4 + 0] = sP[0] + sP[5]; P[h * 4 + 1] = sP[1] + sP[6];
            P[h * 4 + 2] = sP[2] + sP[7]; P[h * 4 + 3] = sP[3] + sP[8];
            if (h == 0) *biasC = linb[0] + sP[4] + sP[9];
        }
    } else {
        int i = (b - 6762) * 256 + t;
        if (i < NPROT) head[i] = -1;
    }
}

// ---------- adjacency: single-pass linked list ----------
__global__ void k_link(const int* __restrict__ src, const int* __restrict__ dst,
                       int* __restrict__ head, int2* __restrict__ elist) {
    int e = blockIdx.x * 256 + threadIdx.x;
    if (e < EPPI) {
        int d = dst[e];
        int prev = atomicExch(&head[d], e);
        elist[e] = make_int2(src[e], prev);
    }
}

// ---------- layer-1 neighbor mean: chain-walk gather Xb -> Am (bf16) ----------
// quarter-wave (16 lanes x bf16x8) per node; chain hop = one broadcast 8B load
__global__ void k_agg(const __bf16* __restrict__ Xb, const int* __restrict__ head,
                      const int2* __restrict__ elist, __bf16* __restrict__ Am) {
    int wave = threadIdx.x >> 6, lane = threadIdx.x & 63;
    int q = lane >> 4, sl = lane & 15;
    int node = blockIdx.x * 16 + wave * 4 + q;
    if (node >= NPROT) return;
    float a[8];
#pragma unroll
    for (int e8 = 0; e8 < 8; e8++) a[e8] = 0.f;
    const __bf16* base = Xb + (size_t)sl * 8;
    int e = head[node];
    int c = 0;
    while (e >= 0) {
        int2 el = elist[e];
        bf16x8 v = *(const bf16x8*)(base + (size_t)el.x * 128);
#pragma unroll
        for (int e8 = 0; e8 < 8; e8++) a[e8] += (float)v[e8];
        c++;
        e = el.y;
    }
    float iv = 1.0f / (float)(c > 1 ? c : 1);
    bf16x8 o;
#pragma unroll
    for (int e8 = 0; e8 < 8; e8++) o[e8] = (__bf16)(a[e8] * iv);
    *(bf16x8*)(Am + (size_t)node * 128 + sl * 8) = o;
}

// ---------- GEMM z = [Am|Xb] @ Bw^T (+ab), relu, project onto P -> y[node][4] ----------
// 128 rows/block, 32 rows/wave. A fragments register-resident. B staged per 64-col
// chunk in fragment-major LDS layout via global_load_lds (lane-linear: zero conflicts,
// no VGPR round-trip).
__global__ __launch_bounds__(256) void k_gemm(const __bf16* __restrict__ Am,
                                              const __bf16* __restrict__ Xb,
                                              const __bf16* __restrict__ Bw,
                                              const float* __restrict__ ab,
                                              const float* __restrict__ P,
                                              float* __restrict__ y) {
    __shared__ __bf16 Bs[2048 * 8];   // 32 KB
    int tid = threadIdx.x;
    int wave = tid >> 6, lane = tid & 63;
    int r = lane & 15, quad = lane >> 4;
    int row0 = blockIdx.x * 128 + wave * 32;

    // A fragments: kk 0..3 -> mean (Am), kk 4..7 -> own (Xb)
    bf16x8 afrag[2][8];
#pragma unroll
    for (int g = 0; g < 2; g++) {
        const __bf16* mp = Am + (size_t)(row0 + g * 16 + r) * 128 + quad * 8;
        const __bf16* op = Xb + (size_t)(row0 + g * 16 + r) * 128 + quad * 8;
#pragma unroll
        for (int kk = 0; kk < 4; kk++) {
            afrag[g][kk]     = *(const bf16x8*)(mp + kk * 32);
            afrag[g][4 + kk] = *(const bf16x8*)(op + kk * 32);
        }
    }

    float part[2][4][4] = {{{0.f}}};

    for (int chunk = 0; chunk < 4; chunk++) {
        if (chunk) __syncthreads();
#pragma unroll
        for (int jj = 0; jj < 8; jj++) {
            int g = jj * 256 + tid;
            int gr = g & 15, gq = (g >> 4) & 3;
            int gkk = (g >> 6) & 7;
            int gt = g >> 9;
            const __bf16* src = Bw + (size_t)(chunk * 64 + gt * 16 + gr) * 256 + gkk * 32 + gq * 8;
            __builtin_amdgcn_global_load_lds(
                (const __attribute__((address_space(1))) void*)src,
                (__attribute__((address_space(3))) void*)(Bs + (size_t)g * 8),
                16, 0, 0);
        }
        __syncthreads();

        floatx4 acc[2][4];
#pragma unroll
        for (int g = 0; g < 2; g++)
#pragma unroll
            for (int t = 0; t < 4; t++) acc[g][t] = (floatx4){0.f, 0.f, 0.f, 0.f};
#pragma unroll
        for (int kk = 0; kk < 8; kk++) {
#pragma unroll
            for (int t = 0; t < 4; t++) {
                bf16x8 bf = *(const bf16x8*)(Bs + (size_t)((t * 8 + kk) * 64 + lane) * 8);
                acc[0][t] = __builtin_amdgcn_mfma_f32_16x16x32_bf16(afrag[0][kk], bf, acc[0][t], 0, 0, 0);
                acc[1][t] = __builtin_amdgcn_mfma_f32_16x16x32_bf16(afrag[1][kk], bf, acc[1][t], 0, 0, 0);
            }
        }

        // epilogue: h = relu(z + ab[col]); accumulate projection onto P
#pragma unroll
        for (int t = 0; t < 4; t++) {
            int col = chunk * 64 + t * 16 + r;
            float bias = ab[col];
            float4 pv = *(const float4*)(P + col * 4);
#pragma unroll
            for (int g = 0; g < 2; g++)
#pragma unroll
                for (int rr = 0; rr < 4; rr++) {
                    float h = acc[g][t][rr] + bias;
                    h = h > 0.f ? h : 0.f;
                    part[g][rr][0] += h * pv.x; part[g][rr][1] += h * pv.y;
                    part[g][rr][2] += h * pv.z; part[g][rr][3] += h * pv.w;
                }
        }
    }

    // reduce over the 16 col-lanes (r); store 32 rows per wave
#pragma unroll
    for (int m = 1; m < 16; m <<= 1)
#pragma unroll
        for (int g = 0; g < 2; g++)
#pragma unroll
            for (int rr = 0; rr < 4; rr++)
#pragma unroll
                for (int j = 0; j < 4; j++)
                    part[g][rr][j] += __shfl_xor(part[g][rr][j], m, 64);
    if (r == 0) {
#pragma unroll
        for (int g = 0; g < 2; g++)
#pragma unroll
            for (int rr = 0; rr < 4; rr++) {
                int row = row0 + g * 16 + quad * 4 + rr;
                float4 o;
                o.x = part[g][rr][0]; o.y = part[g][rr][1];
                o.z = part[g][rr][2]; o.w = part[g][rr][3];
                *(float4*)(y + (size_t)row * 4) = o;
            }
    }
}

// ---------- head: per masked node, chain-walk sum of scalar projections ----------
__global__ void k_head(const int* __restrict__ mask, const int* __restrict__ head,
                       const int2* __restrict__ elist, const float* __restrict__ y,
                       const float* __restrict__ biasC, float* __restrict__ out) {
    int tid = blockIdx.x * 256 + threadIdx.x;
    int p = tid >> 1, side = tid & 1;
    float res = 0.f;
    if (p < NPAIR) {
        int node = mask[p * 2 + side];
        int e = head[node];
        float s = 0.f;
        int c = 0;
        while (e >= 0) {
            int2 el = elist[e];
            s += y[(size_t)el.x * 4 + side];
            c++;
            e = el.y;
        }
        float iv = 1.0f / (float)(c > 1 ? c : 1);
        res = s * iv + y[(size_t)node * 4 + 2 + side];
    }
    float other = __shfl_xor(res, 1, 64);
    if (p < NPAIR && side == 0) {
        float z = res + other + *biasC;
        out[p] = 1.f / (1.f + expf(-z));
    }
}

extern "C" void kernel_launch(void* const* d_in, const int* in_sizes, int n_in,
                              void* d_out, int out_size, void* d_ws, size_t ws_size,
                              hipStream_t stream) {
    const float* x_protein = (const float*)d_in[0];
    const float* a_ppi_Wl  = (const float*)d_in[11];
    const float* a_ppi_b   = (const float*)d_in[12];
    const float* a_ppi_Wr  = (const float*)d_in[13];
    const float* b_ppi_Wl  = (const float*)d_in[23];
    const float* b_ppi_b   = (const float*)d_in[24];
    const float* b_ppi_Wr  = (const float*)d_in[25];
    const float* lin_W     = (const float*)d_in[26];
    const float* lin_b     = (const float*)d_in[27];
    const int* ppi_src     = (const int*)d_in[34];
    const int* ppi_dst     = (const int*)d_in[35];
    const int* mask        = (const int*)d_in[36];
    float* out = (float*)d_out;

    char* ws = (char*)d_ws;
    size_t o = 0;
    auto alloc = [&](size_t n) -> char* {
        char* r = ws + o;
        o = (o + n + 511) & ~(size_t)511;
        return r;
    };
    int*    head   = (int*)alloc((size_t)NPROT * 4);
    int2*   elist  = (int2*)alloc((size_t)EPPI * 8);
    __bf16* Xb     = (__bf16*)alloc((size_t)NPROT_PAD * 128 * 2);
    __bf16* Am     = (__bf16*)alloc((size_t)NPROT_PAD * 128 * 2);
    __bf16* Bw     = (__bf16*)alloc(256 * 256 * 2);
    float*  P      = (float*)alloc(256 * 4 * 4);
    float*  biasC  = (float*)alloc(4);
    float*  y      = (float*)alloc((size_t)NPROT_PAD * 4 * 4);
    (void)ws_size;

    k_prep<<<6958, 256, 0, stream>>>(x_protein, a_ppi_Wl, a_ppi_Wr, lin_W, lin_b,
                                     b_ppi_Wl, b_ppi_Wr, b_ppi_b,
                                     Xb, Bw, P, biasC, head);
    k_link<<<(EPPI + 255) / 256, 256, 0, stream>>>(ppi_src, ppi_dst, head, elist);
    k_agg<<<(NPROT + 15) / 16, 256, 0, stream>>>(Xb, head, elist, Am);
    k_gemm<<<(NPROT_PAD + 127) / 128, 256, 0, stream>>>(Am, Xb, Bw, a_ppi_b, P, y);
    k_head<<<(2 * NPAIR + 255) / 256, 256, 0, stream>>>(mask, head, elist, y, biasC, out);
}